// Round 10
// baseline (1131.231 us; speedup 1.0000x reference)
//
#include <hip/hip_runtime.h>
#include <hip/hip_cooperative_groups.h>
#include <math.h>

namespace cg = cooperative_groups;

#define DD 128
#define COUT 40
#define BN_EPS 1e-5f
#define L2_EPS 1e-12f

typedef __attribute__((ext_vector_type(8))) short bf16x8;
typedef __attribute__((ext_vector_type(4))) float f32x4;

static __device__ inline unsigned short f2bf(float f) {
    unsigned int x = __float_as_uint(f);
    unsigned int r = (x + 0x7FFFu + ((x >> 16) & 1u)) >> 16;   // RNE
    return (unsigned short)r;
}
static __device__ inline float bf2f(unsigned short u) {
    return __uint_as_float(((unsigned int)u) << 16);
}

struct MegaParams {
    const float* x; const int* ei;
    const float *W1, *b1, *W2, *b2, *W3, *b3;
    const float *g1, *be1, *g2, *be2, *g3, *be3;
    const float *Wout, *bout;
    float* out;
    unsigned short *linb, *aggA, *aggB, *hbf1, *hbf2, *wb, *wob;
    int *colidx, *deg, *fill, *row_ptr;
    float* dinv;
    int *bsum, *boff;
    float* stats;
    int N, E, NB;
};

// ---- stage helpers (all called by every thread of every block) ----

// agg + fused BN-stats. lin rows pre-scaled by dinv[src]; out = bias + dv*sum.
static __device__ __forceinline__ void st_agg(const unsigned short* __restrict__ lin,
                                              const int* __restrict__ row_ptr,
                                              const int* __restrict__ boff,
                                              const int* __restrict__ colidx,
                                              const float* __restrict__ dinv,
                                              const float* __restrict__ bias,
                                              unsigned short* __restrict__ outb,
                                              float* __restrict__ gstats,
                                              float* lstats, int N) {
    const int tid = threadIdx.x;
    lstats[tid] = 0.f;
    __syncthreads();
    const int slot = (tid >> 6) * 2 + ((tid & 63) >> 5);
    const int c = (tid & 31) * 4;
    float s0 = 0, s1 = 0, s2 = 0, s3 = 0, q0 = 0, q1 = 0, q2 = 0, q3 = 0;
    const int VB = (N + 7) / 8;
    for (int vb = blockIdx.x; vb < VB; vb += gridDim.x) {
        int v = vb * 8 + slot;
        if (v >= N) continue;
        int s = row_ptr[v] + boff[v >> 8];
        int e = row_ptr[v + 1] + boff[(v + 1) >> 8];
        float dv = dinv[v];
        float4 a0 = make_float4(0.f, 0.f, 0.f, 0.f);
        float4 a1 = make_float4(0.f, 0.f, 0.f, 0.f);
        float4 a2 = make_float4(0.f, 0.f, 0.f, 0.f);
        float4 a3 = make_float4(0.f, 0.f, 0.f, 0.f);
        int j = s;
        for (; j + 3 < e; j += 4) {
            int u0 = colidx[j], u1 = colidx[j + 1], u2 = colidx[j + 2], u3 = colidx[j + 3];
            ushort4 t0 = *(const ushort4*)&lin[(size_t)u0 * DD + c];
            ushort4 t1 = *(const ushort4*)&lin[(size_t)u1 * DD + c];
            ushort4 t2 = *(const ushort4*)&lin[(size_t)u2 * DD + c];
            ushort4 t3 = *(const ushort4*)&lin[(size_t)u3 * DD + c];
            a0.x += bf2f(t0.x); a0.y += bf2f(t0.y); a0.z += bf2f(t0.z); a0.w += bf2f(t0.w);
            a1.x += bf2f(t1.x); a1.y += bf2f(t1.y); a1.z += bf2f(t1.z); a1.w += bf2f(t1.w);
            a2.x += bf2f(t2.x); a2.y += bf2f(t2.y); a2.z += bf2f(t2.z); a2.w += bf2f(t2.w);
            a3.x += bf2f(t3.x); a3.y += bf2f(t3.y); a3.z += bf2f(t3.z); a3.w += bf2f(t3.w);
        }
        for (; j < e; ++j) {
            int u = colidx[j];
            ushort4 t = *(const ushort4*)&lin[(size_t)u * DD + c];
            a0.x += bf2f(t.x); a0.y += bf2f(t.y); a0.z += bf2f(t.z); a0.w += bf2f(t.w);
        }
        float4 bi = *(const float4*)&bias[c];
        float ox = bi.x + dv * (a0.x + a1.x + a2.x + a3.x);
        float oy = bi.y + dv * (a0.y + a1.y + a2.y + a3.y);
        float oz = bi.z + dv * (a0.z + a1.z + a2.z + a3.z);
        float ow = bi.w + dv * (a0.w + a1.w + a2.w + a3.w);
        s0 += ox; s1 += oy; s2 += oz; s3 += ow;
        q0 += ox * ox; q1 += oy * oy; q2 += oz * oz; q3 += ow * ow;
        ushort4 o;
        o.x = f2bf(ox); o.y = f2bf(oy); o.z = f2bf(oz); o.w = f2bf(ow);
        *(ushort4*)&outb[(size_t)v * DD + c] = o;
    }
    atomicAdd(&lstats[c], s0); atomicAdd(&lstats[c + 1], s1);
    atomicAdd(&lstats[c + 2], s2); atomicAdd(&lstats[c + 3], s3);
    atomicAdd(&lstats[128 + c], q0); atomicAdd(&lstats[128 + c + 1], q1);
    atomicAdd(&lstats[128 + c + 2], q2); atomicAdd(&lstats[128 + c + 3], q3);
    __syncthreads();
    atomicAdd(&gstats[tid], lstats[tid]);
}

// h = l2norm(relu(bn(aggX)) [+res]); hbf_out = bf16(h); linb_out = dinv_r*(h@W)
template <bool HAS_RES>
static __device__ __forceinline__ void st_fused(const unsigned short* __restrict__ aggX,
                                                const float* __restrict__ stats,
                                                const float* __restrict__ g,
                                                const float* __restrict__ be, float inv_n,
                                                const unsigned short* __restrict__ resb,
                                                const unsigned short* __restrict__ Wb,
                                                const float* __restrict__ dinv,
                                                unsigned short* __restrict__ hbf_out,
                                                unsigned short* __restrict__ linb_out,
                                                unsigned short* Ws, float* ssl, int N) {
    const int tid = threadIdx.x;
    for (int i = tid; i < 2048; i += 256) ((uint4*)Ws)[i] = ((const uint4*)Wb)[i];
    if (tid < 128) {
        float mu = stats[tid] * inv_n;
        float var = stats[128 + tid] * inv_n - mu * mu;
        float sc = g[tid] * rsqrtf(var + BN_EPS);
        ssl[tid] = sc;
        ssl[128 + tid] = be[tid] - mu * sc;
    }
    __syncthreads();
    const int wv = tid >> 6, lane = tid & 63, m = lane & 15, q = lane >> 4;
    const int NC = (N + 63) / 64;
    for (int cb = blockIdx.x; cb < NC; cb += gridDim.x) {
        int R0 = cb * 64 + wv * 16;
        if (R0 >= N) continue;
        int rr = R0 + m; if (rr >= N) rr = N - 1;
        const unsigned short* Ar = aggX + (size_t)rr * DD + q * 8;
        const unsigned short* Rr = HAS_RES ? resb + (size_t)rr * DD + q * 8 : nullptr;
        float y[4][8];
        float sq = 0.f;
#pragma unroll
        for (int kc = 0; kc < 4; kc++) {
            ushort4 lo = *(const ushort4*)(Ar + kc * 32);
            ushort4 hi = *(const ushort4*)(Ar + kc * 32 + 4);
            unsigned short av[8] = {lo.x, lo.y, lo.z, lo.w, hi.x, hi.y, hi.z, hi.w};
            int c0 = kc * 32 + q * 8;
            float4 sc0 = *(const float4*)&ssl[c0];
            float4 sc1 = *(const float4*)&ssl[c0 + 4];
            float4 sh0 = *(const float4*)&ssl[128 + c0];
            float4 sh1 = *(const float4*)&ssl[128 + c0 + 4];
            float scv[8] = {sc0.x, sc0.y, sc0.z, sc0.w, sc1.x, sc1.y, sc1.z, sc1.w};
            float shv[8] = {sh0.x, sh0.y, sh0.z, sh0.w, sh1.x, sh1.y, sh1.z, sh1.w};
            if (HAS_RES) {
                ushort4 rl = *(const ushort4*)(Rr + kc * 32);
                ushort4 rh = *(const ushort4*)(Rr + kc * 32 + 4);
                unsigned short rv[8] = {rl.x, rl.y, rl.z, rl.w, rh.x, rh.y, rh.z, rh.w};
#pragma unroll
                for (int j = 0; j < 8; j++) {
                    float yy = fmaxf(bf2f(av[j]) * scv[j] + shv[j], 0.f) + bf2f(rv[j]);
                    y[kc][j] = yy; sq += yy * yy;
                }
            } else {
#pragma unroll
                for (int j = 0; j < 8; j++) {
                    float yy = fmaxf(bf2f(av[j]) * scv[j] + shv[j], 0.f);
                    y[kc][j] = yy; sq += yy * yy;
                }
            }
        }
        sq += __shfl_xor(sq, 16, 64);
        sq += __shfl_xor(sq, 32, 64);
        float inv = 1.f / fmaxf(sqrtf(sq), L2_EPS);
        bf16x8 af[4];
#pragma unroll
        for (int kc = 0; kc < 4; kc++) {
            unsigned short t[8];
#pragma unroll
            for (int j = 0; j < 8; j++) t[j] = f2bf(y[kc][j] * inv);
            af[kc] = *(const bf16x8*)t;
            *(bf16x8*)&hbf_out[(size_t)rr * DD + q * 8 + kc * 32] = af[kc];
        }
        f32x4 acc[8];
#pragma unroll
        for (int cc = 0; cc < 8; cc++) acc[cc] = (f32x4){0.f, 0.f, 0.f, 0.f};
#pragma unroll
        for (int kc = 0; kc < 4; kc++)
#pragma unroll
            for (int cc = 0; cc < 8; cc++) {
                bf16x8 b = *(const bf16x8*)&Ws[(size_t)((kc * 8 + cc) * 64 + lane) * 8];
                acc[cc] = __builtin_amdgcn_mfma_f32_16x16x32_bf16(af[kc], b, acc[cc], 0, 0, 0);
            }
        float dr[4];
#pragma unroll
        for (int i = 0; i < 4; i++) {
            int r = R0 + q * 4 + i;
            dr[i] = (r < N) ? dinv[r] : 0.f;
        }
#pragma unroll
        for (int cc = 0; cc < 8; cc++)
#pragma unroll
            for (int i = 0; i < 4; i++) {
                int r = R0 + q * 4 + i;
                if (r < N) linb_out[(size_t)r * DD + cc * 16 + m] = f2bf(acc[cc][i] * dr[i]);
            }
    }
}

// ---- the single cooperative kernel ----

__global__ __launch_bounds__(256) void k_mega(MegaParams p) {
    cg::grid_group grid = cg::this_grid();
    const int tid = threadIdx.x;
    const int gid = blockIdx.x * 256 + tid;
    const int gsz = gridDim.x * 256;

    __shared__ __align__(16) unsigned short Ws[16384];   // 32 KB
    __shared__ __align__(16) float ssl[256];             // 1 KB (also scan / lstats)
    int* si = (int*)ssl;

    // ---- S0: weight repack + zero stats/deg/fill ----
    for (int i = gid; i < 6144; i += gsz) {
        int wi = i >> 11;
        int idx = i & 2047;
        const float* W = (wi == 0) ? p.W1 : (wi == 1) ? p.W2 : p.W3;
        int kc = idx >> 9, cc = (idx >> 6) & 7, lane = idx & 63;
        int n = cc * 16 + (lane & 15);
        int kb = kc * 32 + (lane >> 4) * 8;
        unsigned short tmp[8];
#pragma unroll
        for (int j = 0; j < 8; j++) tmp[j] = f2bf(W[(size_t)(kb + j) * DD + n]);
        *(uint4*)&p.wb[(size_t)(wi * 16384 + idx * 8)] = *(const uint4*)tmp;
    }
    for (int i = gid; i < 768; i += gsz) {
        int kc = i / 192, rem = i % 192;
        int cc = rem >> 6, lane = rem & 63;
        int n = cc * 16 + (lane & 15);
        int kb = kc * 32 + (lane >> 4) * 8;
        unsigned short tmp[8];
#pragma unroll
        for (int j = 0; j < 8; j++)
            tmp[j] = (n < COUT) ? f2bf(p.Wout[(size_t)(kb + j) * COUT + n]) : 0;
        *(uint4*)&p.wob[(size_t)i * 8] = *(const uint4*)tmp;
    }
    for (int i = gid; i < 768; i += gsz) p.stats[i] = 0.f;
    int zn4 = (2 * p.N) / 4;       // deg+fill contiguous, N multiple of 4
    for (int i = gid; i < zn4; i += gsz) ((int4*)p.deg)[i] = make_int4(0, 0, 0, 0);
    grid.sync();

    // ---- S1: degree histogram ----
    for (int i = gid; i < p.E; i += gsz) atomicAdd(&p.deg[p.ei[p.E + i]], 1);
    grid.sync();

    // ---- S2: per-chunk exclusive scan of (deg+1), chunk totals, dinv ----
    for (int b = blockIdx.x; b < p.NB; b += gridDim.x) {
        int idx = b * 256 + tid;
        int v = (idx < p.N) ? p.deg[idx] + 1 : 0;
        if (idx < p.N) p.dinv[idx] = rsqrtf((float)v);
        si[tid] = v; __syncthreads();
        for (int off = 1; off < 256; off <<= 1) {
            int xx = (tid >= off) ? si[tid - off] : 0;
            __syncthreads(); si[tid] += xx; __syncthreads();
        }
        if (idx <= p.N) p.row_ptr[idx] = si[tid] - v;
        if (tid == 255) p.bsum[b] = si[255];
        __syncthreads();
    }
    grid.sync();

    // ---- S3: scan chunk totals -> boff (block 0, tiled) ----
    if (blockIdx.x == 0) {
        int carry = 0;
        for (int t0 = 0; t0 < p.NB; t0 += 256) {
            int i = t0 + tid;
            int v = (i < p.NB) ? p.bsum[i] : 0;
            si[tid] = v; __syncthreads();
            for (int off = 1; off < 256; off <<= 1) {
                int xx = (tid >= off) ? si[tid - off] : 0;
                __syncthreads(); si[tid] += xx; __syncthreads();
            }
            if (i < p.NB) p.boff[i] = si[tid] - v + carry;
            carry += si[255];
            __syncthreads();
        }
    }
    grid.sync();

    // ---- S4: CSR fill (colidx only; lin pre-scaled later) ----
    {
        int total = p.E + p.N;
        for (int i = gid; i < total; i += gsz) {
            int u, v;
            if (i < p.E) { u = p.ei[i]; v = p.ei[p.E + i]; }
            else { u = i - p.E; v = u; }
            int pp = atomicAdd(&p.fill[v], 1);
            p.colidx[p.row_ptr[v] + p.boff[v >> 8] + pp] = u;
        }
    }
    grid.sync();

    // ---- S5: gemm0  linb = dinv_r * (x @ W1) ----
    {
        for (int i = tid; i < 2048; i += 256) ((uint4*)Ws)[i] = ((const uint4*)p.wb)[i];
        __syncthreads();
        const int wv = tid >> 6, lane = tid & 63, m = lane & 15, q = lane >> 4;
        const int NC = (p.N + 63) / 64;
        for (int cb = blockIdx.x; cb < NC; cb += gridDim.x) {
            int R0 = cb * 64 + wv * 16;
            if (R0 >= p.N) continue;
            int rr = R0 + m; if (rr >= p.N) rr = p.N - 1;
            const float* Ar = p.x + (size_t)rr * DD + q * 8;
            bf16x8 af[4];
#pragma unroll
            for (int kc = 0; kc < 4; kc++) {
                float4 lo = *(const float4*)(Ar + kc * 32);
                float4 hi = *(const float4*)(Ar + kc * 32 + 4);
                unsigned short t[8];
                t[0] = f2bf(lo.x); t[1] = f2bf(lo.y); t[2] = f2bf(lo.z); t[3] = f2bf(lo.w);
                t[4] = f2bf(hi.x); t[5] = f2bf(hi.y); t[6] = f2bf(hi.z); t[7] = f2bf(hi.w);
                af[kc] = *(const bf16x8*)t;
            }
            f32x4 acc[8];
#pragma unroll
            for (int cc = 0; cc < 8; cc++) acc[cc] = (f32x4){0.f, 0.f, 0.f, 0.f};
#pragma unroll
            for (int kc = 0; kc < 4; kc++)
#pragma unroll
                for (int cc = 0; cc < 8; cc++) {
                    bf16x8 b = *(const bf16x8*)&Ws[(size_t)((kc * 8 + cc) * 64 + lane) * 8];
                    acc[cc] = __builtin_amdgcn_mfma_f32_16x16x32_bf16(af[kc], b, acc[cc], 0, 0, 0);
                }
            float dr[4];
#pragma unroll
            for (int i = 0; i < 4; i++) {
                int r = R0 + q * 4 + i;
                dr[i] = (r < p.N) ? p.dinv[r] : 0.f;
            }
#pragma unroll
            for (int cc = 0; cc < 8; cc++)
#pragma unroll
                for (int i = 0; i < 4; i++) {
                    int r = R0 + q * 4 + i;
                    if (r < p.N) p.linb[(size_t)r * DD + cc * 16 + m] = f2bf(acc[cc][i] * dr[i]);
                }
        }
    }
    grid.sync();

    float inv_n = 1.0f / (float)p.N;

    // ---- layer 1: agg (+stats1) ----
    st_agg(p.linb, p.row_ptr, p.boff, p.colidx, p.dinv, p.b1, p.aggA, p.stats, ssl, p.N);
    grid.sync();
    // ---- fused1: BN1+relu+l2 -> hbf1; linb = dinv*(h1 @ W2) ----
    st_fused<false>(p.aggA, p.stats, p.g1, p.be1, inv_n, nullptr,
                    p.wb + 16384, p.dinv, p.hbf1, p.linb, Ws, ssl, p.N);
    grid.sync();
    // ---- layer 2: agg (+stats2) ----
    st_agg(p.linb, p.row_ptr, p.boff, p.colidx, p.dinv, p.b2, p.aggB, p.stats + 256, ssl, p.N);
    grid.sync();
    // ---- fused2: BN2+relu+res(hbf1)+l2 -> hbf2; linb = dinv*(h2 @ W3) ----
    st_fused<true>(p.aggB, p.stats + 256, p.g2, p.be2, inv_n, p.hbf1,
                   p.wb + 32768, p.dinv, p.hbf2, p.linb, Ws, ssl, p.N);
    grid.sync();
    // ---- layer 3: agg (+stats3) ----
    st_agg(p.linb, p.row_ptr, p.boff, p.colidx, p.dinv, p.b3, p.aggA, p.stats + 512, ssl, p.N);
    grid.sync();

    // ---- output: BN3+relu+res(hbf2)+l2; logits = h3 @ Wout + bout ----
    {
        for (int i = tid; i < 768; i += 256) ((uint4*)Ws)[i] = ((const uint4*)p.wob)[i];
        if (tid < 128) {
            float mu = p.stats[512 + tid] * inv_n;
            float var = p.stats[512 + 128 + tid] * inv_n - mu * mu;
            float sc = p.g3[tid] * rsqrtf(var + BN_EPS);
            ssl[tid] = sc;
            ssl[128 + tid] = p.be3[tid] - mu * sc;
        }
        __syncthreads();
        const int wv = tid >> 6, lane = tid & 63, m = lane & 15, q = lane >> 4;
        const int NC = (p.N + 63) / 64;
        for (int cb = blockIdx.x; cb < NC; cb += gridDim.x) {
            int R0 = cb * 64 + wv * 16;
            if (R0 >= p.N) continue;
            int rr = R0 + m; if (rr >= p.N) rr = p.N - 1;
            const unsigned short* Ar = p.aggA + (size_t)rr * DD + q * 8;
            const unsigned short* Rr = p.hbf2 + (size_t)rr * DD + q * 8;
            float y[4][8];
            float sq = 0.f;
#pragma unroll
            for (int kc = 0; kc < 4; kc++) {
                ushort4 lo = *(const ushort4*)(Ar + kc * 32);
                ushort4 hi = *(const ushort4*)(Ar + kc * 32 + 4);
                ushort4 rl = *(const ushort4*)(Rr + kc * 32);
                ushort4 rh = *(const ushort4*)(Rr + kc * 32 + 4);
                unsigned short av[8] = {lo.x, lo.y, lo.z, lo.w, hi.x, hi.y, hi.z, hi.w};
                unsigned short rv[8] = {rl.x, rl.y, rl.z, rl.w, rh.x, rh.y, rh.z, rh.w};
                int c0 = kc * 32 + q * 8;
                float4 sc0 = *(const float4*)&ssl[c0];
                float4 sc1 = *(const float4*)&ssl[c0 + 4];
                float4 sh0 = *(const float4*)&ssl[128 + c0];
                float4 sh1 = *(const float4*)&ssl[128 + c0 + 4];
                float scv[8] = {sc0.x, sc0.y, sc0.z, sc0.w, sc1.x, sc1.y, sc1.z, sc1.w};
                float shv[8] = {sh0.x, sh0.y, sh0.z, sh0.w, sh1.x, sh1.y, sh1.z, sh1.w};
#pragma unroll
                for (int j = 0; j < 8; j++) {
                    float yy = fmaxf(bf2f(av[j]) * scv[j] + shv[j], 0.f) + bf2f(rv[j]);
                    y[kc][j] = yy; sq += yy * yy;
                }
            }
            sq += __shfl_xor(sq, 16, 64);
            sq += __shfl_xor(sq, 32, 64);
            float inv = 1.f / fmaxf(sqrtf(sq), L2_EPS);
            bf16x8 af[4];
#pragma unroll
            for (int kc = 0; kc < 4; kc++) {
                unsigned short t[8];
#pragma unroll
                for (int j = 0; j < 8; j++) t[j] = f2bf(y[kc][j] * inv);
                af[kc] = *(const bf16x8*)t;
            }
            f32x4 acc[3];
#pragma unroll
            for (int cc = 0; cc < 3; cc++) acc[cc] = (f32x4){0.f, 0.f, 0.f, 0.f};
#pragma unroll
            for (int kc = 0; kc < 4; kc++)
#pragma unroll
                for (int cc = 0; cc < 3; cc++) {
                    bf16x8 b = *(const bf16x8*)&Ws[(size_t)((kc * 3 + cc) * 64 + lane) * 8];
                    acc[cc] = __builtin_amdgcn_mfma_f32_16x16x32_bf16(af[kc], b, acc[cc], 0, 0, 0);
                }
#pragma unroll
            for (int cc = 0; cc < 3; cc++) {
                int col = cc * 16 + m;
                if (col < COUT) {
                    float bb = p.bout[col];
#pragma unroll
                    for (int i = 0; i < 4; i++) {
                        int r = R0 + q * 4 + i;
                        if (r < p.N) p.out[(size_t)r * COUT + col] = acc[cc][i] + bb;
                    }
                }
            }
        }
    }
}

// ---------------- host ----------------

extern "C" void kernel_launch(void* const* d_in, const int* in_sizes, int n_in,
                              void* d_out, int out_size, void* d_ws, size_t ws_size,
                              hipStream_t stream) {
    MegaParams p;
    p.x    = (const float*)d_in[0];
    p.ei   = (const int*)d_in[1];
    p.W1   = (const float*)d_in[2];  p.b1  = (const float*)d_in[3];
    p.W2   = (const float*)d_in[4];  p.b2  = (const float*)d_in[5];
    p.W3   = (const float*)d_in[6];  p.b3  = (const float*)d_in[7];
    p.g1   = (const float*)d_in[8];  p.be1 = (const float*)d_in[9];
    p.g2   = (const float*)d_in[10]; p.be2 = (const float*)d_in[11];
    p.g3   = (const float*)d_in[12]; p.be3 = (const float*)d_in[13];
    p.Wout = (const float*)d_in[14]; p.bout = (const float*)d_in[15];
    p.out  = (float*)d_out;

    const int N = in_sizes[0] / DD;
    const int E = in_sizes[1] / 2;
    const int NNZ = E + N;
    p.N = N; p.E = E; p.NB = (N + 1 + 255) / 256;

    char* w = (char*)d_ws;
    p.linb = (unsigned short*)w;  w += (size_t)N * DD * sizeof(unsigned short);
    p.aggA = (unsigned short*)w;  w += (size_t)N * DD * sizeof(unsigned short);
    p.aggB = (unsigned short*)w;  w += (size_t)N * DD * sizeof(unsigned short);
    p.hbf1 = (unsigned short*)w;  w += (size_t)N * DD * sizeof(unsigned short);
    p.hbf2 = (unsigned short*)w;  w += (size_t)N * DD * sizeof(unsigned short);
    p.wb   = (unsigned short*)w;  w += 3 * 16384 * sizeof(unsigned short);
    p.wob  = (unsigned short*)w;  w += 6144 * sizeof(unsigned short);
    p.colidx = (int*)w;           w += (size_t)NNZ * sizeof(int);
    p.deg  = (int*)w;             w += (size_t)N * sizeof(int);   // deg+fill contiguous
    p.fill = (int*)w;             w += (size_t)N * sizeof(int);
    p.row_ptr = (int*)w;          w += (size_t)(N + 1) * sizeof(int);
    p.dinv = (float*)w;           w += (size_t)N * sizeof(float);
    p.bsum = (int*)w;             w += 512 * sizeof(int);
    p.boff = (int*)w;             w += 512 * sizeof(int);
    p.stats = (float*)w;          w += 768 * sizeof(float);

    // persistent-grid size: co-resident capacity (deterministic each call)
    int occ = 0;
    hipOccupancyMaxActiveBlocksPerMultiprocessor(&occ, (const void*)k_mega, 256, 0);
    if (occ < 1) occ = 1;
    int dev = 0;
    hipGetDevice(&dev);
    hipDeviceProp_t props;
    hipGetDeviceProperties(&props, dev);
    int G = occ * props.multiProcessorCount;
    if (G < 1) G = 256;

    void* args[] = {&p};
    hipLaunchCooperativeKernel((void*)k_mega, dim3(G), dim3(256), args, 0, stream);
}